// Round 3
// baseline (301.950 us; speedup 1.0000x reference)
//
#include <hip/hip_runtime.h>
#include <hip/hip_bf16.h>
#include <stdint.h>

typedef __attribute__((ext_vector_type(8))) short short8;
typedef __attribute__((ext_vector_type(4))) float f32x4;

#define T_DIM 256
#define NBATCH 64

__device__ __forceinline__ void gload_lds16(const void* g, void* l) {
    __builtin_amdgcn_global_load_lds(
        (const __attribute__((address_space(1))) void*)g,
        (__attribute__((address_space(3))) void*)l, 16, 0, 0);
}

// ---------------- prep: W [(K+1)][O] fp32 -> WT_hi/WT_lo [O][K] bf16 + bias[O] ----
__global__ void prep_w(const float* __restrict__ W, __hip_bfloat16* __restrict__ WTh,
                       __hip_bfloat16* __restrict__ WTl, float* __restrict__ bias,
                       int K, int O) {
    int idx = blockIdx.x * blockDim.x + threadIdx.x;
    int total = O * K;
    if (idx < total) {
        int o = idx / K, i = idx % K;
        float w = W[(size_t)i * O + o];
        __hip_bfloat16 h = __float2bfloat16(w);
        WTh[idx] = h;
        WTl[idx] = __float2bfloat16(w - __bfloat162float(h));
    }
    if (idx < O) bias[idx] = W[(size_t)K * O + idx];
}

// ---------------- prep: x [64][512][256] fp32 -> xh/xl [64][256][512] bf16 --------
__global__ void prep_x(const float* __restrict__ x, __hip_bfloat16* __restrict__ xh,
                       __hip_bfloat16* __restrict__ xl) {
    __shared__ float tile[32][33];
    int b = blockIdx.z;
    int i0 = blockIdx.x * 32;   // input-dim 512
    int t0 = blockIdx.y * 32;   // time 256
    int tx = threadIdx.x;       // 0..31
    int ty = threadIdx.y;       // 0..7
    for (int dy = 0; dy < 32; dy += 8)
        tile[ty + dy][tx] = x[((size_t)b * 512 + i0 + ty + dy) * T_DIM + t0 + tx];
    __syncthreads();
    for (int dy = 0; dy < 32; dy += 8) {
        float w = tile[tx][ty + dy];
        size_t dst = ((size_t)b * T_DIM + t0 + ty + dy) * 512 + i0 + tx;
        __hip_bfloat16 h = __float2bfloat16(w);
        xh[dst] = h;
        xl[dst] = __float2bfloat16(w - __bfloat162float(h));
    }
}

// ---------------- batched multi-pass GEMM + fused LIF -----------------------------
// Tile: 128 (o) x 256 (t = ALL timesteps) x BK=64, 8 waves (2 M x 4 N), per-wave
// 64x64, acc[4][4]. One block owns a batch's entire time axis -> LIF scan fused in
// the epilogue (Sout != nullptr): acc -> LDS in 64-t chunks, 128 threads scan t
// carrying mem in a register, emit bf16 spikes in [b][t][o] (next GEMM's B layout).
// If Sout == nullptr: write pre-activations fp32 to Cout [b][t][o] (final layer).
// XCD mapping: xcd = bid&7 owns batches [xcd*8, xcd*8+8).
__global__ __launch_bounds__(512) void gemm_fused(
    const __hip_bfloat16* __restrict__ A0, const __hip_bfloat16* __restrict__ A1,
    const __hip_bfloat16* __restrict__ A2,
    const __hip_bfloat16* __restrict__ B0, const __hip_bfloat16* __restrict__ B1,
    const __hip_bfloat16* __restrict__ B2,
    const float* __restrict__ bias, float* __restrict__ Cout,
    __hip_bfloat16* __restrict__ Sout,
    const float* __restrict__ beta_p, const float* __restrict__ thr_p,
    int O, int K, int npass, int nOx) {
    __shared__ __align__(16) char pool[49152];
    __hip_bfloat16* As = (__hip_bfloat16*)pool;            // 128 rows x 128 B = 16 KB
    __hip_bfloat16* Bs = (__hip_bfloat16*)(pool + 16384);  // 256 rows x 128 B = 32 KB

    // XCD-aware decomposition (grid = 64 * nOx, batches_per_xcd = 8)
    const int fid = blockIdx.x;
    const int xcd = fid & 7;
    const int k_in = fid >> 3;
    const int b = xcd * 8 + k_in / nOx;
    const int o0 = (k_in % nOx) * 128;

    const int tid = threadIdx.x;
    const int lane = tid & 63;
    const int wave = tid >> 6;       // 0..7
    const int wm = wave >> 2;        // 0..1  (o)
    const int wn = wave & 3;         // 0..3  (t)

    const __hip_bfloat16* Ap[3] = {A0, A1, A2};
    const __hip_bfloat16* Bp[3] = {B0, B1, B2};

    f32x4 acc[4][4] = {};

    const int srow = tid >> 3;         // 0..63
    const int skb  = (tid & 7) * 16;   // linear dest byte within 128B row

    for (int p = 0; p < npass; ++p) {
        const __hip_bfloat16* Aptr = Ap[p];
        const __hip_bfloat16* Bptr = Bp[p] + (size_t)b * T_DIM * K;
        for (int k0 = 0; k0 < K; k0 += 64) {
            // stage A[o0..o0+127][k0..+63], B[0..255][k0..+63]
            // LDS[row][kb] = G[row][kb ^ ((row&7)<<4)] (pre-swizzled src, linear dest)
            int src_kb = skb ^ ((srow & 7) << 4);
#pragma unroll
            for (int r = 0; r < 2; ++r) {
                int row = srow + r * 64;
                gload_lds16((const char*)(Aptr + (size_t)(o0 + row) * K + k0) + src_kb,
                            (char*)As + row * 128 + skb);
            }
#pragma unroll
            for (int r = 0; r < 4; ++r) {
                int row = srow + r * 64;
                gload_lds16((const char*)(Bptr + (size_t)row * K + k0) + src_kb,
                            (char*)Bs + row * 128 + skb);
            }
            __syncthreads();
#pragma unroll
            for (int kk = 0; kk < 2; ++kk) {
                short8 af[4], bfr[4];
#pragma unroll
                for (int i = 0; i < 4; ++i) {
                    int row = wm * 64 + i * 16 + (lane & 15);
                    int kb = (((lane >> 4) * 8) + kk * 32) * 2;
                    kb ^= (row & 7) << 4;
                    af[i] = *(const short8*)((const char*)As + row * 128 + kb);
                }
#pragma unroll
                for (int j = 0; j < 4; ++j) {
                    int row = wn * 64 + j * 16 + (lane & 15);
                    int kb = (((lane >> 4) * 8) + kk * 32) * 2;
                    kb ^= (row & 7) << 4;
                    bfr[j] = *(const short8*)((const char*)Bs + row * 128 + kb);
                }
#pragma unroll
                for (int i = 0; i < 4; ++i)
#pragma unroll
                    for (int j = 0; j < 4; ++j)
                        acc[i][j] = __builtin_amdgcn_mfma_f32_16x16x32_bf16(
                            af[i], bfr[j], acc[i][j], 0, 0, 0);
            }
            __syncthreads();
        }
    }

    // ---------------- epilogue ----------------
    // D layout [m89]: col(t)=lane&15, row(o)=(lane>>4)*4+r
    if (Sout == nullptr) {
        // final layer: pre = acc + bias -> Cout [b][t][o], one float4/lane
#pragma unroll
        for (int i = 0; i < 4; ++i) {
            int ob = o0 + wm * 64 + i * 16 + ((lane >> 4) * 4);
            f32x4 bv = *(const f32x4*)(bias + ob);
#pragma unroll
            for (int j = 0; j < 4; ++j) {
                int t = wn * 64 + j * 16 + (lane & 15);
                *(f32x4*)(Cout + ((size_t)b * T_DIM + t) * O + ob) = acc[i][j] + bv;
            }
        }
        return;
    }

    // fused LIF: 4 chunks of 64 t; waves with wn==tc dump acc+bias to LDS [t][o]
    // (pad 129 floats -> conflict-free), then threads 0..127 (one per o) scan.
    float sb = 1.f / (1.f + expf(-beta_p[0]));
    float thrv = thr_p[0];
    float* fpool = (float*)pool;   // 64 * 129 * 4 = 33 KB, aliases As/Bs (done)
    float mem = 0.f;
    for (int tc = 0; tc < 4; ++tc) {
        __syncthreads();   // previous chunk fully consumed (or K-loop done)
        if (wn == tc) {
#pragma unroll
            for (int i = 0; i < 4; ++i) {
                int o = wm * 64 + i * 16 + ((lane >> 4) * 4);
                f32x4 bv = *(const f32x4*)(bias + o0 + o);
#pragma unroll
                for (int j = 0; j < 4; ++j) {
                    int tt = j * 16 + (lane & 15);   // 0..63 within chunk
                    *(f32x4*)(fpool + tt * 129 + o) = acc[i][j] + bv;
                }
            }
        }
        __syncthreads();
        if (tid < 128) {
            int o = o0 + tid;
#pragma unroll 8
            for (int tt = 0; tt < 64; ++tt) {
                float mu = __fadd_rn(__fmul_rn(sb, mem), fpool[tt * 129 + tid]);
                float spike = (mu >= thrv) ? 1.f : 0.f;
                mem = mu - spike * thrv;
                Sout[((size_t)b * T_DIM + tc * 64 + tt) * O + o] = __float2bfloat16(spike);
            }
        }
    }
}

// ---------------- LIF scan: final layer -------------------------------------------
// pre [b][t][256] fp32 -> out spikes [b][256][t], mems [b][256][t] fp32
__global__ void lif_final(const float* __restrict__ pre, float* __restrict__ osp,
                          float* __restrict__ omem, const float* __restrict__ beta_p,
                          const float* __restrict__ thr_p) {
    int idx = blockIdx.x * blockDim.x + threadIdx.x;  // b*256 + o  (16384 total)
    int b = idx >> 8, o = idx & 255;
    float sb = 1.f / (1.f + expf(-beta_p[0]));
    float thr = thr_p[0];
    float mem = 0.f;
    const float* src = pre + (size_t)b * T_DIM * 256 + o;
    float* ds = osp + (size_t)idx * T_DIM;
    float* dm = omem + (size_t)idx * T_DIM;
    for (int t = 0; t < T_DIM; ++t) {
        dm[t] = mem;  // mem entering this timestep
        float mu = __fadd_rn(__fmul_rn(sb, mem), src[(size_t)t * 256]);
        float spike = (mu >= thr) ? 1.f : 0.f;
        ds[t] = spike;
        mem = mu - spike * thr;
    }
}

extern "C" void kernel_launch(void* const* d_in, const int* in_sizes, int n_in,
                              void* d_out, int out_size, void* d_ws, size_t ws_size,
                              hipStream_t stream) {
    const float* x  = (const float*)d_in[0];
    const float* W0 = (const float*)d_in[1];
    const float* W1 = (const float*)d_in[2];
    const float* W2 = (const float*)d_in[3];
    const float* beta = (const float*)d_in[4];
    const float* thr  = (const float*)d_in[5];
    float* out = (float*)d_out;

    char* ws = (char*)d_ws;
    size_t off = 0;
    auto alloc = [&](size_t bytes) {
        size_t r = off;
        off = (off + bytes + 255) & ~(size_t)255;
        return r;
    };
    __hip_bfloat16* w0h = (__hip_bfloat16*)(ws + alloc(1024 * 512 * 2));
    __hip_bfloat16* w0l = (__hip_bfloat16*)(ws + alloc(1024 * 512 * 2));
    float* b0 = (float*)(ws + alloc(1024 * 4));
    __hip_bfloat16* w1h = (__hip_bfloat16*)(ws + alloc(1024 * 1024 * 2));
    __hip_bfloat16* w1l = (__hip_bfloat16*)(ws + alloc(1024 * 1024 * 2));
    float* b1 = (float*)(ws + alloc(1024 * 4));
    __hip_bfloat16* w2h = (__hip_bfloat16*)(ws + alloc(256 * 1024 * 2));
    __hip_bfloat16* w2l = (__hip_bfloat16*)(ws + alloc(256 * 1024 * 2));
    float* b2 = (float*)(ws + alloc(256 * 4));
    __hip_bfloat16* xh = (__hip_bfloat16*)(ws + alloc((size_t)NBATCH * T_DIM * 512 * 2));
    __hip_bfloat16* xl = (__hip_bfloat16*)(ws + alloc((size_t)NBATCH * T_DIM * 512 * 2));
    __hip_bfloat16* S1 = (__hip_bfloat16*)(ws + alloc((size_t)NBATCH * T_DIM * 1024 * 2));
    __hip_bfloat16* S2 = (__hip_bfloat16*)(ws + alloc((size_t)NBATCH * T_DIM * 1024 * 2));
    float* pre = (float*)(ws + alloc((size_t)NBATCH * T_DIM * 256 * 4));
    (void)ws_size; (void)in_sizes; (void)n_in; (void)out_size;

    // prep weights
    prep_w<<<(1024 * 512 + 255) / 256, 256, 0, stream>>>(W0, w0h, w0l, b0, 512, 1024);
    prep_w<<<(1024 * 1024 + 255) / 256, 256, 0, stream>>>(W1, w1h, w1l, b1, 1024, 1024);
    prep_w<<<(256 * 1024 + 255) / 256, 256, 0, stream>>>(W2, w2h, w2l, b2, 1024, 256);
    // prep x (transpose + split)
    prep_x<<<dim3(16, 8, 64), dim3(32, 8), 0, stream>>>(x, xh, xl);

    // Layer 1: O=1024, K=512, 3 passes: xh*Wh + xl*Wh + xh*Wl  (grid = 64*8)
    gemm_fused<<<dim3(512), 512, 0, stream>>>(w0h, w0h, w0l, xh, xl, xh,
                                              b0, nullptr, S1, beta, thr,
                                              1024, 512, 3, 8);
    // Layer 2: O=1024, K=1024, 2 passes: S1*Wh + S1*Wl
    gemm_fused<<<dim3(512), 512, 0, stream>>>(w1h, w1l, w1l, S1, S1, S1,
                                              b1, nullptr, S2, beta, thr,
                                              1024, 1024, 2, 8);
    // Layer 3: O=256, K=1024, 2 passes -> pre (fp32), then final LIF
    gemm_fused<<<dim3(128), 512, 0, stream>>>(w2h, w2l, w2l, S2, S2, S2,
                                              b2, pre, nullptr, beta, thr,
                                              256, 1024, 2, 2);
    lif_final<<<(NBATCH * 256) / 256, 256, 0, stream>>>(pre, out, out + (size_t)NBATCH * 256 * T_DIM,
                                                        beta, thr);
}

// Round 4
// 271.003 us; speedup vs baseline: 1.1142x; 1.1142x over previous
//
#include <hip/hip_runtime.h>
#include <hip/hip_bf16.h>
#include <stdint.h>

typedef __attribute__((ext_vector_type(8))) short short8;
typedef __attribute__((ext_vector_type(4))) float f32x4;

#define T_DIM 256
#define NBATCH 64

__device__ __forceinline__ void gload_lds16(const void* g, void* l) {
    __builtin_amdgcn_global_load_lds(
        (const __attribute__((address_space(1))) void*)g,
        (__attribute__((address_space(3))) void*)l, 16, 0, 0);
}

// ---------------- prep: W [(K+1)][O] fp32 -> WT_hi/WT_lo [O][K] bf16 + bias[O] ----
__global__ void prep_w(const float* __restrict__ W, __hip_bfloat16* __restrict__ WTh,
                       __hip_bfloat16* __restrict__ WTl, float* __restrict__ bias,
                       int K, int O) {
    int idx = blockIdx.x * blockDim.x + threadIdx.x;
    int total = O * K;
    if (idx < total) {
        int o = idx / K, i = idx % K;
        float w = W[(size_t)i * O + o];
        __hip_bfloat16 h = __float2bfloat16(w);
        WTh[idx] = h;
        WTl[idx] = __float2bfloat16(w - __bfloat162float(h));
    }
    if (idx < O) bias[idx] = W[(size_t)K * O + idx];
}

// ---------------- prep: x [64][512][256] fp32 -> xh/xl [64][256][512] bf16 --------
__global__ void prep_x(const float* __restrict__ x, __hip_bfloat16* __restrict__ xh,
                       __hip_bfloat16* __restrict__ xl) {
    __shared__ float tile[32][33];
    int b = blockIdx.z;
    int i0 = blockIdx.x * 32;   // input-dim 512
    int t0 = blockIdx.y * 32;   // time 256
    int tx = threadIdx.x;       // 0..31
    int ty = threadIdx.y;       // 0..7
    for (int dy = 0; dy < 32; dy += 8)
        tile[ty + dy][tx] = x[((size_t)b * 512 + i0 + ty + dy) * T_DIM + t0 + tx];
    __syncthreads();
    for (int dy = 0; dy < 32; dy += 8) {
        float w = tile[tx][ty + dy];
        size_t dst = ((size_t)b * T_DIM + t0 + ty + dy) * 512 + i0 + tx;
        __hip_bfloat16 h = __float2bfloat16(w);
        xh[dst] = h;
        xl[dst] = __float2bfloat16(w - __bfloat162float(h));
    }
}

// ---------------- batched multi-pass GEMM ----------------------------------------
// pre[b][t][o] = sum_p A_p[o][:]·B_p[b][t][:] + bias[o]   (C layout [b][t][o])
// A planes: bf16 [O][K]; B planes: bf16 [NBATCH][T_DIM][K]; tile 128 x BN, BK=64
// 4 waves (2 M x 2 N), per-wave 64 x BN/2. XCD mapping: xcd = bid&7 owns batches
// [xcd*8, xcd*8+8); within a batch tiles processed contiguously -> L2 locality.
template <int BN>
__global__ __launch_bounds__(256) void gemm_mfma(
    const __hip_bfloat16* __restrict__ A0, const __hip_bfloat16* __restrict__ A1,
    const __hip_bfloat16* __restrict__ A2,
    const __hip_bfloat16* __restrict__ B0, const __hip_bfloat16* __restrict__ B1,
    const __hip_bfloat16* __restrict__ B2,
    const float* __restrict__ bias, float* __restrict__ Cout,
    int O, int K, int npass, int nOx, int nTy) {
    constexpr int NB = BN / 32;   // t-frags per wave
    __shared__ __hip_bfloat16 As[128 * 64];
    __shared__ __hip_bfloat16 Bs[BN * 64];

    // XCD-aware decomposition (grid = 64 * nOx * nTy, batches_per_xcd = 8)
    const int fid = blockIdx.x;
    const int bpb = nOx * nTy;            // blocks per batch
    const int xcd = fid & 7;
    const int k_in = fid >> 3;
    const int b = xcd * 8 + k_in / bpb;
    const int r_in = k_in % bpb;
    const int o0 = (r_in / nTy) * 128;
    const int t0 = (r_in % nTy) * BN;

    const int tid = threadIdx.x;
    const int lane = tid & 63;
    const int wave = tid >> 6;
    const int wm = wave >> 1, wn = wave & 1;

    const __hip_bfloat16* Ap[3] = {A0, A1, A2};
    const __hip_bfloat16* Bp[3] = {B0, B1, B2};

    f32x4 acc[4][NB] = {};

    const int srow = tid >> 3;         // 0..31 (row within 32-row stage chunk)
    const int skb  = (tid & 7) * 16;   // linear dest byte within 128B row

    for (int p = 0; p < npass; ++p) {
        const __hip_bfloat16* Aptr = Ap[p];
        const __hip_bfloat16* Bptr = Bp[p] + (size_t)b * T_DIM * K;
        for (int k0 = 0; k0 < K; k0 += 64) {
            // stage A[o0..o0+127][k0..+63], B[t0..t0+BN-1][k0..+63]
            // LDS[row][kb] = G[row][kb ^ ((row&7)<<4)] (pre-swizzled src, linear dest)
            int src_kb = skb ^ ((srow & 7) << 4);
#pragma unroll
            for (int r = 0; r < 4; ++r) {
                int row = srow + r * 32;
                gload_lds16((const char*)(Aptr + (size_t)(o0 + row) * K + k0) + src_kb,
                            (char*)As + row * 128 + skb);
            }
#pragma unroll
            for (int r = 0; r < NB; ++r) {
                int row = srow + r * 32;
                gload_lds16((const char*)(Bptr + (size_t)(t0 + row) * K + k0) + src_kb,
                            (char*)Bs + row * 128 + skb);
            }
            __syncthreads();
#pragma unroll
            for (int kk = 0; kk < 2; ++kk) {
                short8 af[4], bfr[NB];
#pragma unroll
                for (int i = 0; i < 4; ++i) {
                    int row = wm * 64 + i * 16 + (lane & 15);
                    int kb = (((lane >> 4) * 8) + kk * 32) * 2;
                    kb ^= (row & 7) << 4;
                    af[i] = *(const short8*)((const char*)As + row * 128 + kb);
                }
#pragma unroll
                for (int j = 0; j < NB; ++j) {
                    int row = wn * (BN / 2) + j * 16 + (lane & 15);
                    int kb = (((lane >> 4) * 8) + kk * 32) * 2;
                    kb ^= (row & 7) << 4;
                    bfr[j] = *(const short8*)((const char*)Bs + row * 128 + kb);
                }
#pragma unroll
                for (int i = 0; i < 4; ++i)
#pragma unroll
                    for (int j = 0; j < NB; ++j)
                        acc[i][j] = __builtin_amdgcn_mfma_f32_16x16x32_bf16(
                            af[i], bfr[j], acc[i][j], 0, 0, 0);
            }
            __syncthreads();
        }
    }
    // epilogue: D col(t)=lane&15, row(o)=(lane>>4)*4+r   [m89 layout]
    // C layout [b][t][o]: the 4 r's are contiguous floats -> one float4 store/lane
#pragma unroll
    for (int i = 0; i < 4; ++i) {
        int ob = o0 + wm * 64 + i * 16 + ((lane >> 4) * 4);
        f32x4 bv = *(const f32x4*)(bias + ob);
#pragma unroll
        for (int j = 0; j < NB; ++j) {
            int t = t0 + wn * (BN / 2) + j * 16 + (lane & 15);
            f32x4 v = acc[i][j] + bv;
            *(f32x4*)(Cout + ((size_t)b * T_DIM + t) * O + ob) = v;
        }
    }
}

// ---------------- LIF scan: hidden layers -----------------------------------------
// pre [b][t][o] fp32 -> spikes S [b][t][o] bf16.  Thread = (b,o); reads/writes
// coalesced across the wave at every t step.
__global__ void lif_hidden(const float* __restrict__ pre, __hip_bfloat16* __restrict__ st,
                           const float* __restrict__ beta_p, const float* __restrict__ thr_p,
                           int O) {
    int idx = blockIdx.x * blockDim.x + threadIdx.x;  // b*O + o
    int b = idx / O, o = idx - b * O;
    float sb = 1.f / (1.f + expf(-beta_p[0]));
    float thr = thr_p[0];
    float mem = 0.f;
    const float* src = pre + (size_t)b * T_DIM * O + o;
    __hip_bfloat16* dst = st + (size_t)b * T_DIM * O + o;
    for (int t = 0; t < T_DIM; ++t) {
        float mu = __fadd_rn(__fmul_rn(sb, mem), src[(size_t)t * O]);
        float spike = (mu >= thr) ? 1.f : 0.f;
        mem = mu - spike * thr;
        dst[(size_t)t * O] = __float2bfloat16(spike);
    }
}

// ---------------- LIF scan: final layer (LDS-transposed coalesced writes) ---------
// pre [b][t][256] fp32 -> out spikes [b][256][t], mems [b][256][t] fp32.
// 1 wave per 64 neurons (grid 256 -> 1 block/CU). Scan 32-t chunks: prefetch the
// chunk's pre values to registers (decouple loads from serial mem chain), scan into
// LDS [64 o][33], flush with lanes along t -> 128B-contiguous stores.
__global__ __launch_bounds__(64) void lif_final_t(
    const float* __restrict__ pre, float* __restrict__ osp, float* __restrict__ omem,
    const float* __restrict__ beta_p, const float* __restrict__ thr_p) {
    __shared__ float spk[64][33];
    __shared__ float mm[64][33];
    int bid = blockIdx.x;          // 0..255
    int b = bid >> 2, og = bid & 3;
    int lane = threadIdx.x;        // 0..63
    float sb = 1.f / (1.f + expf(-beta_p[0]));
    float thr = thr_p[0];
    float mem = 0.f;
    const float* src = pre + (size_t)b * T_DIM * 256 + og * 64 + lane;
    int bo = b * 256 + og * 64;
    for (int c = 0; c < 8; ++c) {
        int t0 = c * 32;
        float xv[32];
#pragma unroll
        for (int tt = 0; tt < 32; ++tt)
            xv[tt] = src[(size_t)(t0 + tt) * 256];
#pragma unroll
        for (int tt = 0; tt < 32; ++tt) {
            mm[lane][tt] = mem;   // mem entering this timestep
            float mu = __fadd_rn(__fmul_rn(sb, mem), xv[tt]);
            float spike = (mu >= thr) ? 1.f : 0.f;
            spk[lane][tt] = spike;
            mem = mu - spike * thr;
        }
        // flush: 2 o-rows per iteration, lanes cover 32 consecutive t
#pragma unroll
        for (int it = 0; it < 32; ++it) {
            int row = (lane >> 5) + 2 * it;
            int col = lane & 31;
            size_t dst = ((size_t)bo + row) * T_DIM + t0 + col;
            osp[dst] = spk[row][col];
            omem[dst] = mm[row][col];
        }
    }
}

extern "C" void kernel_launch(void* const* d_in, const int* in_sizes, int n_in,
                              void* d_out, int out_size, void* d_ws, size_t ws_size,
                              hipStream_t stream) {
    const float* x  = (const float*)d_in[0];
    const float* W0 = (const float*)d_in[1];
    const float* W1 = (const float*)d_in[2];
    const float* W2 = (const float*)d_in[3];
    const float* beta = (const float*)d_in[4];
    const float* thr  = (const float*)d_in[5];
    float* out = (float*)d_out;

    char* ws = (char*)d_ws;
    size_t off = 0;
    auto alloc = [&](size_t bytes) {
        size_t r = off;
        off = (off + bytes + 255) & ~(size_t)255;
        return r;
    };
    __hip_bfloat16* w0h = (__hip_bfloat16*)(ws + alloc(1024 * 512 * 2));
    __hip_bfloat16* w0l = (__hip_bfloat16*)(ws + alloc(1024 * 512 * 2));
    float* b0 = (float*)(ws + alloc(1024 * 4));
    __hip_bfloat16* w1h = (__hip_bfloat16*)(ws + alloc(1024 * 1024 * 2));
    __hip_bfloat16* w1l = (__hip_bfloat16*)(ws + alloc(1024 * 1024 * 2));
    float* b1 = (float*)(ws + alloc(1024 * 4));
    __hip_bfloat16* w2h = (__hip_bfloat16*)(ws + alloc(256 * 1024 * 2));
    __hip_bfloat16* w2l = (__hip_bfloat16*)(ws + alloc(256 * 1024 * 2));
    float* b2 = (float*)(ws + alloc(256 * 4));
    __hip_bfloat16* xh = (__hip_bfloat16*)(ws + alloc((size_t)NBATCH * T_DIM * 512 * 2));
    __hip_bfloat16* xl = (__hip_bfloat16*)(ws + alloc((size_t)NBATCH * T_DIM * 512 * 2));
    __hip_bfloat16* S  = (__hip_bfloat16*)(ws + alloc((size_t)NBATCH * T_DIM * 1024 * 2));
    float* pre = (float*)(ws + alloc((size_t)NBATCH * T_DIM * 1024 * 4));
    (void)ws_size; (void)in_sizes; (void)n_in; (void)out_size;

    // prep weights
    prep_w<<<(1024 * 512 + 255) / 256, 256, 0, stream>>>(W0, w0h, w0l, b0, 512, 1024);
    prep_w<<<(1024 * 1024 + 255) / 256, 256, 0, stream>>>(W1, w1h, w1l, b1, 1024, 1024);
    prep_w<<<(256 * 1024 + 255) / 256, 256, 0, stream>>>(W2, w2h, w2l, b2, 1024, 256);
    // prep x (transpose + split)
    prep_x<<<dim3(16, 8, 64), dim3(32, 8), 0, stream>>>(x, xh, xl);

    // Layer 1: O=1024, K=512, 3 passes: xh*Wh + xl*Wh + xh*Wl  (grid = 64*16)
    gemm_mfma<128><<<dim3(1024), 256, 0, stream>>>(w0h, w0h, w0l, xh, xl, xh,
                                                   b0, pre, 1024, 512, 3, 8, 2);
    lif_hidden<<<(NBATCH * 1024) / 256, 256, 0, stream>>>(pre, S, beta, thr, 1024);

    // Layer 2: O=1024, K=1024, 2 passes: S*Wh + S*Wl
    gemm_mfma<128><<<dim3(1024), 256, 0, stream>>>(w1h, w1l, w1l, S, S, S,
                                                   b1, pre, 1024, 1024, 2, 8, 2);
    lif_hidden<<<(NBATCH * 1024) / 256, 256, 0, stream>>>(pre, S, beta, thr, 1024);

    // Layer 3: O=256, K=1024, 2 passes, BN=64 -> grid 512 (2 blocks/CU)
    gemm_mfma<64><<<dim3(512), 256, 0, stream>>>(w2h, w2l, w2l, S, S, S,
                                                 b2, pre, 256, 1024, 2, 2, 4);
    lif_final_t<<<dim3(256), 64, 0, stream>>>(pre, out, out + (size_t)NBATCH * 256 * T_DIM,
                                              beta, thr);
}